// Round 5
// baseline (1819.171 us; speedup 1.0000x reference)
//
#include <hip/hip_runtime.h>
#include <hip/hip_bf16.h>

// Problem constants (from reference)
#define NN 16384
#define EE 65536
#define DD 64
#define HH 128
#define LL 3
#define GG 512
#define OUTD 128
#define NEG 0.01f   // jax.nn.leaky_relu default slope

#define SK 512      // kd per slice (8 k x 64 d)
#define NSLICE 16
#define PADW 520    // SK + 8 bf16 pad -> row stride 1040B == shift-4 banks

typedef __attribute__((ext_vector_type(8))) short short8;
typedef __attribute__((ext_vector_type(4))) float f32x4;

__device__ __forceinline__ float leaky(float x){ return x > 0.f ? x : NEG * x; }
__device__ __forceinline__ unsigned short f2bf(float f){
  union { float f; unsigned int u; } v; v.f = f;
  unsigned int r = v.u + 0x7fffu + ((v.u >> 16) & 1u);   // RNE
  return (unsigned short)(r >> 16);
}

// ---------------- CSR build ----------------
__global__ void k_deg(const int* ei, int* deg){
  int e = blockIdx.x*256 + threadIdx.x;
  if (e < EE) atomicAdd(&deg[ei[EE + e]], 1);   // row 1 of edge_index = dst
}
__global__ void k_cnt(const int* batch, int* cnt){
  int n = blockIdx.x*256 + threadIdx.x;
  if (n < NN) atomicAdd(&cnt[batch[n]], 1);
}
__global__ void k_scan(const int* deg, int* row_ptr){
  __shared__ int part[256];
  int t = threadIdx.x;
  int base = t*64; int s = 0;
  for (int i=0;i<64;++i) s += deg[base+i];
  part[t] = s; __syncthreads();
  for (int off=1; off<256; off<<=1){
    int v = (t>=off)?part[t-off]:0; __syncthreads();
    part[t] += v; __syncthreads();
  }
  int run = (t==0)?0:part[t-1];
  if (t==0) row_ptr[0] = 0;
  for (int i=0;i<64;++i){ run += deg[base+i]; row_ptr[base+i+1] = run; }
}
__global__ void k_fill(const int* ei, const int* row_ptr, int* cursor,
                       int* edge_id, int* src_sorted){
  int e = blockIdx.x*256 + threadIdx.x;
  if (e < EE){
    int d = ei[EE + e];
    int pos = row_ptr[d] + atomicAdd(&cursor[d], 1);
    edge_id[pos] = e;
    src_sorted[pos] = ei[e];      // row 0 of edge_index = src
  }
}

// ---------------- one-time bf16 prep: ea and W1^T ----------------
__global__ void k_prep_ea(const float* ea, unsigned short* eab){
  int i = blockIdx.x*256 + threadIdx.x;   // EE*DD
  eab[i] = f2bf(ea[i]);
}
__global__ void k_prep_w1t(const float* W1, unsigned short* W1T){
  int i = blockIdx.x*256 + threadIdx.x;   // LL*HH*DD
  int l = i >> 13, r = i & 8191;
  int j = r >> 6, d = r & 63;
  W1T[i] = f2bf(W1[(size_t)l*DD*HH + d*HH + j]);   // W1T[l][j][d]
}

// ---------------- LayerNorm + leaky ----------------
__global__ void k_ln(const float* x, const float* scale, const float* bias, float* h, int l){
  int t = threadIdx.x, lane = t & 63, nl = t >> 6;
  int n = blockIdx.x*4 + nl;
  float v = x[(size_t)n*DD + lane];
  float s = v;
  for (int m=1;m<64;m<<=1) s += __shfl_xor(s, m, 64);
  float mu = s * (1.0f/64.0f);
  float dv = v - mu;
  float q = dv*dv;
  for (int m=1;m<64;m<<=1) q += __shfl_xor(q, m, 64);
  float var = q * (1.0f/64.0f);
  float w = dv * rsqrtf(var + 1e-5f) * scale[l*DD + lane] + bias[l*DD + lane];
  h[(size_t)n*DD + lane] = leaky(w);
}

// ---------------- edge MLP via MFMA: ug = bf16(leaky(ea @ W1[l] + b1[l]))  [E,128] ----------
__global__ __launch_bounds__(256, 2)
void k_edge_mlp(const unsigned short* eab, const unsigned short* W1T, const float* b1,
                unsigned short* ug, int l){
  __shared__ __align__(16) unsigned short a_lds[128][72];   // ea tile  [e][d]
  __shared__ __align__(16) unsigned short b_lds[128][72];   // W1T      [j][d]
  __shared__ __align__(16) unsigned short c_lds[128][136];  // out      [e][j]
  int t = threadIdx.x;
  int e0 = blockIdx.x * 128;
  {
    int row = t >> 1, col = (t & 1) * 32;
    const float4* sa = (const float4*)(eab + (size_t)(e0 + row)*DD + col);
    const float4* sb = (const float4*)(W1T + (size_t)l*HH*DD + (size_t)row*DD + col);
    #pragma unroll
    for (int i=0;i<4;++i){
      *(float4*)&a_lds[row][col + 8*i] = sa[i];
      *(float4*)&b_lds[row][col + 8*i] = sb[i];
    }
  }
  __syncthreads();
  int wave = t >> 6, lane = t & 63;
  int m0 = (wave >> 1) * 64, j0 = (wave & 1) * 64;
  int lr = lane & 15, lq = lane >> 4;
  f32x4 acc[4][4];
  #pragma unroll
  for (int a=0;a<4;++a)
    #pragma unroll
    for (int b=0;b<4;++b) acc[a][b] = (f32x4){0.f,0.f,0.f,0.f};
  #pragma unroll
  for (int ks=0; ks<2; ++ks){
    short8 av[4];
    #pragma unroll
    for (int mt=0; mt<4; ++mt) av[mt] = *(const short8*)&a_lds[m0 + mt*16 + lr][ks*32 + lq*8];
    #pragma unroll
    for (int jt=0; jt<4; ++jt){
      short8 bv = *(const short8*)&b_lds[j0 + jt*16 + lr][ks*32 + lq*8];
      #pragma unroll
      for (int mt=0; mt<4; ++mt)
        acc[mt][jt] = __builtin_amdgcn_mfma_f32_16x16x32_bf16(av[mt], bv, acc[mt][jt], 0, 0, 0);
    }
  }
  // C/D: col = lane&15, row = (lane>>4)*4 + r
  #pragma unroll
  for (int mt=0; mt<4; ++mt)
    #pragma unroll
    for (int jt=0; jt<4; ++jt){
      int col = j0 + jt*16 + lr;
      float bj = b1[l*HH + col];
      #pragma unroll
      for (int r=0; r<4; ++r){
        int row = m0 + mt*16 + lq*4 + r;
        c_lds[row][col] = f2bf(leaky(acc[mt][jt][r] + bj));
      }
    }
  __syncthreads();
  {
    int row = t >> 1, half = t & 1;
    float4* dst = (float4*)(ug + (size_t)(e0 + row)*HH + half*64);
    #pragma unroll
    for (int i=0;i<8;++i) dst[i] = *(const float4*)&c_lds[row][half*64 + 8*i];
  }
}

// ---------------- W2[l] -> bf16 transposed [f][kd]  (kd = k*64+d, contiguous K) ----------------
__global__ void k_w2t(const float* W2, unsigned short* W2T, int l){
  int idx = blockIdx.x*256 + threadIdx.x;    // < 64*8192
  int f = idx >> 13, kd = idx & 8191;
  W2T[idx] = f2bf(W2[(size_t)l*HH*DD*DD + (size_t)kd*DD + f]);
}

// ---------------- FUSED conv: per-block 64 nodes, slice kd, build S-slice in LDS,
// MFMA against staged W2T slice, C resident in regs across slices. No S in HBM,
// no atomics. Grid = NN/64 = 256 blocks.
__global__ __launch_bounds__(256, 1)
void k_conv(const unsigned short* ug, const float* h, const unsigned short* W2T,
            const int* row_ptr, const int* edge_id, const int* src_sorted,
            float* num, float* Hs){
  __shared__ __align__(16) unsigned short s_lds[64][PADW];  // S slice [node][k*64+d]
  __shared__ __align__(16) unsigned short w_lds[64][PADW];  // W2T slice [f][c]
  int t = threadIdx.x, wave = t >> 6, lane = t & 63;
  int lr = lane & 15, lq = lane >> 4;
  int nbase = blockIdx.x * 64;
  f32x4 acc[4];
  #pragma unroll
  for (int i=0;i<4;++i) acc[i] = (f32x4){0.f,0.f,0.f,0.f};

  for (int s=0; s<NSLICE; ++s){
    // ---- stage W2T slice: rows f=0..63, cols [512s, 512s+512)
    {
      int r = t >> 2, q = t & 3;
      const float4* src = (const float4*)(W2T + (size_t)r*8192 + s*SK + q*128);
      float4* dst = (float4*)&w_lds[r][q*128];
      #pragma unroll
      for (int i=0;i<16;++i) dst[i] = src[i];
    }
    // ---- phase A: build S slice for wave's 16 nodes, two interleaved chains
    int koff = s*4;   // dword offset in ug row (8 bf16 k's per slice)
    for (int i=0;i<8;++i){
      int na  = nbase + wave*16 + i;
      int nb2 = na + 8;
      int ra = row_ptr[na],  ra1 = row_ptr[na+1];
      int rb = row_ptr[nb2], rb1 = row_ptr[nb2+1];
      float aac[8], bac[8];
      #pragma unroll
      for (int k=0;k<8;++k){ aac[k]=0.f; bac[k]=0.f; }
      float hsa = 0.f, hsb = 0.f;
      while ((ra < ra1) | (rb < rb1)){
        if (ra < ra1){
          int e  = __builtin_amdgcn_readfirstlane(edge_id[ra]);
          int sv = __builtin_amdgcn_readfirstlane(src_sorted[ra]);
          float hv = h[(size_t)sv*DD + lane];
          const unsigned int* up = (const unsigned int*)(ug + (size_t)e*HH) + koff;
          unsigned int w0 = __builtin_amdgcn_readfirstlane(up[0]);
          unsigned int w1 = __builtin_amdgcn_readfirstlane(up[1]);
          unsigned int w2 = __builtin_amdgcn_readfirstlane(up[2]);
          unsigned int w3 = __builtin_amdgcn_readfirstlane(up[3]);
          hsa += hv;
          aac[0] += __uint_as_float(w0 << 16) * hv;
          aac[1] += __uint_as_float(w0 & 0xFFFF0000u) * hv;
          aac[2] += __uint_as_float(w1 << 16) * hv;
          aac[3] += __uint_as_float(w1 & 0xFFFF0000u) * hv;
          aac[4] += __uint_as_float(w2 << 16) * hv;
          aac[5] += __uint_as_float(w2 & 0xFFFF0000u) * hv;
          aac[6] += __uint_as_float(w3 << 16) * hv;
          aac[7] += __uint_as_float(w3 & 0xFFFF0000u) * hv;
          ++ra;
        }
        if (rb < rb1){
          int e  = __builtin_amdgcn_readfirstlane(edge_id[rb]);
          int sv = __builtin_amdgcn_readfirstlane(src_sorted[rb]);
          float hv = h[(size_t)sv*DD + lane];
          const unsigned int* up = (const unsigned int*)(ug + (size_t)e*HH) + koff;
          unsigned int w0 = __builtin_amdgcn_readfirstlane(up[0]);
          unsigned int w1 = __builtin_amdgcn_readfirstlane(up[1]);
          unsigned int w2 = __builtin_amdgcn_readfirstlane(up[2]);
          unsigned int w3 = __builtin_amdgcn_readfirstlane(up[3]);
          hsb += hv;
          bac[0] += __uint_as_float(w0 << 16) * hv;
          bac[1] += __uint_as_float(w0 & 0xFFFF0000u) * hv;
          bac[2] += __uint_as_float(w1 << 16) * hv;
          bac[3] += __uint_as_float(w1 & 0xFFFF0000u) * hv;
          bac[4] += __uint_as_float(w2 << 16) * hv;
          bac[5] += __uint_as_float(w2 & 0xFFFF0000u) * hv;
          bac[6] += __uint_as_float(w3 << 16) * hv;
          bac[7] += __uint_as_float(w3 & 0xFFFF0000u) * hv;
          ++rb;
        }
      }
      int nla = wave*16 + i, nlb = nla + 8;
      #pragma unroll
      for (int k=0;k<8;++k){
        s_lds[nla][k*64 + lane] = f2bf(aac[k]);
        s_lds[nlb][k*64 + lane] = f2bf(bac[k]);
      }
      if (s == 0){
        Hs[(size_t)na*DD  + lane] = hsa;
        Hs[(size_t)nb2*DD + lane] = hsb;
      }
    }
    __syncthreads();
    // ---- phase B: MFMA 16 ksteps x 4 f-tiles; A rows = wave's 16 nodes
    #pragma unroll 4
    for (int kk=0; kk<SK; kk+=32){
      short8 av = *(const short8*)&s_lds[wave*16 + lr][kk + lq*8];
      #pragma unroll
      for (int ft=0; ft<4; ++ft){
        short8 bv = *(const short8*)&w_lds[ft*16 + lr][kk + lq*8];
        acc[ft] = __builtin_amdgcn_mfma_f32_16x16x32_bf16(av, bv, acc[ft], 0, 0, 0);
      }
    }
    __syncthreads();
  }
  // epilogue: C/D layout col=lane&15, row=(lane>>4)*4+r; direct stores (block owns rows)
  #pragma unroll
  for (int ft=0; ft<4; ++ft)
    #pragma unroll
    for (int r=0; r<4; ++r)
      num[(size_t)(nbase + wave*16 + lq*4 + r)*DD + ft*16 + lr] = acc[ft][r];
}

// ---------------- node update: x += num/deg + h@root + Hs@b2 + conv_b ----------------
__global__ void k_update(float* x, const float* num, const float* h, const float* Hs,
                         const int* deg, const float* root, const float* b2,
                         const float* conv_b, int l){
  __shared__ float rl[64][64];
  __shared__ float b2l[64][64];
  __shared__ float hrow[4][64];
  __shared__ float hsrow[4][64];
  int t = threadIdx.x;
  int f = t & 63, nl = t >> 6;
  for (int idx=t; idx<4096; idx+=256){
    rl[idx>>6][idx&63]  = root[(size_t)l*4096 + idx];
    b2l[idx>>6][idx&63] = b2[(size_t)l*4096 + idx];
  }
  int n = blockIdx.x*4 + nl;
  hrow[nl][f]  = h[(size_t)n*DD + f];
  hsrow[nl][f] = Hs[(size_t)n*DD + f];
  __syncthreads();
  float dg = (float)deg[n]; if (dg < 1.f) dg = 1.f;
  float acc = x[(size_t)n*DD + f] + num[(size_t)n*DD + f]/dg + conv_b[l*DD + f];
  #pragma unroll
  for (int d=0; d<64; ++d)
    acc += hrow[nl][d]*rl[d][f] + hsrow[nl][d]*b2l[d][f];
  x[(size_t)n*DD + f] = acc;
}

// ---------------- head: dense + pooled atomic accumulate ----------------
__global__ void k_dense_pool(const float* x, const float* dW, const float* db,
                             const int* batch, float* pooled){
  __shared__ float wl[64][64];
  __shared__ float xrow[4][64];
  int t = threadIdx.x;
  int f = t & 63, nl = t >> 6;
  for (int idx=t; idx<4096; idx+=256) wl[idx>>6][idx&63] = dW[idx];
  int n = blockIdx.x*4 + nl;
  xrow[nl][f] = x[(size_t)n*DD + f];
  __syncthreads();
  float acc = db[f];
  #pragma unroll
  for (int d=0; d<64; ++d) acc += xrow[nl][d]*wl[d][f];
  atomicAdd(&pooled[(size_t)batch[n]*DD + f], acc);
}

__global__ void k_final(const float* pooled, const int* cnt, const float* oW,
                        const float* ob, float* out){
  __shared__ float p[64];
  int g = blockIdx.x, t = threadIdx.x;
  if (t < 64){
    float c = (float)cnt[g]; if (c < 1.f) c = 1.f;
    p[t] = leaky(pooled[(size_t)g*DD + t] / c);
  }
  __syncthreads();
  float acc = ob[t];
  #pragma unroll
  for (int f=0; f<64; ++f) acc += p[f]*oW[(size_t)f*OUTD + t];
  out[(size_t)g*OUTD + t] = acc;
}

// ws too small -> emit ws_size as diagnostic (deterministic per machine)
__global__ void k_diag(float* out, float val, int n){
  int i = blockIdx.x*256 + threadIdx.x;
  if (i < n) out[i] = (i==0) ? val : 0.f;
}

extern "C" void kernel_launch(void* const* d_in, const int* in_sizes, int n_in,
                              void* d_out, int out_size, void* d_ws, size_t ws_size,
                              hipStream_t stream){
  const float* x_in  = (const float*)d_in[0];
  const int*   ei    = (const int*)d_in[1];
  const float* ea    = (const float*)d_in[2];
  const int*   batch = (const int*)d_in[3];
  const float* ln_s  = (const float*)d_in[4];
  const float* ln_b  = (const float*)d_in[5];
  const float* W1    = (const float*)d_in[6];
  const float* b1    = (const float*)d_in[7];
  const float* W2    = (const float*)d_in[8];
  const float* b2    = (const float*)d_in[9];
  const float* root  = (const float*)d_in[10];
  const float* convb = (const float*)d_in[11];
  const float* dW    = (const float*)d_in[12];
  const float* db    = (const float*)d_in[13];
  const float* oW    = (const float*)d_in[14];
  const float* ob    = (const float*)d_in[15];
  float* out = (float*)d_out;

  char* ws = (char*)d_ws;
  size_t off = 0;
  auto alloc = [&](size_t bytes)->char*{
    char* p = ws + off; off = (off + bytes + 255) & ~(size_t)255; return p;
  };
  float* x_cur  = (float*)alloc((size_t)NN*DD*4);
  float* h      = (float*)alloc((size_t)NN*DD*4);
  unsigned short* ug  = (unsigned short*)alloc((size_t)EE*HH*2);
  float* num    = (float*)alloc((size_t)NN*DD*4);
  float* Hs     = (float*)alloc((size_t)NN*DD*4);
  unsigned short* W2T = (unsigned short*)alloc((size_t)8192*64*2);
  unsigned short* eab = (unsigned short*)alloc((size_t)EE*DD*2);
  unsigned short* W1T = (unsigned short*)alloc((size_t)LL*HH*DD*2);
  int* deg     = (int*)alloc((size_t)NN*4);
  int* row_ptr = (int*)alloc((size_t)(NN+1)*4);
  int* cursor  = (int*)alloc((size_t)NN*4);
  int* edge_id = (int*)alloc((size_t)EE*4);
  int* src_sorted = (int*)alloc((size_t)EE*4);
  int* cnt     = (int*)alloc((size_t)GG*4);
  float* pooled= (float*)alloc((size_t)GG*DD*4);
  size_t needed = off;
  if (ws_size < needed){
    k_diag<<<(out_size+255)/256, 256, 0, stream>>>(out, (float)ws_size, out_size);
    return;
  }

  hipMemsetAsync(deg, 0, (size_t)NN*4, stream);
  hipMemsetAsync(cursor, 0, (size_t)NN*4, stream);
  hipMemsetAsync(cnt, 0, (size_t)GG*4, stream);
  hipMemsetAsync(pooled, 0, (size_t)GG*DD*4, stream);
  hipMemcpyAsync(x_cur, x_in, (size_t)NN*DD*4, hipMemcpyDeviceToDevice, stream);

  k_deg <<<EE/256, 256, 0, stream>>>(ei, deg);
  k_cnt <<<NN/256, 256, 0, stream>>>(batch, cnt);
  k_scan<<<1, 256, 0, stream>>>(deg, row_ptr);
  k_fill<<<EE/256, 256, 0, stream>>>(ei, row_ptr, cursor, edge_id, src_sorted);
  k_prep_ea <<<(EE*DD)/256, 256, 0, stream>>>(ea, eab);
  k_prep_w1t<<<(LL*HH*DD)/256, 256, 0, stream>>>(W1, W1T);

  for (int l=0; l<LL; ++l){
    k_ln      <<<NN/4, 256, 0, stream>>>(x_cur, ln_s, ln_b, h, l);
    k_edge_mlp<<<EE/128, 256, 0, stream>>>(eab, W1T, b1, ug, l);
    k_w2t     <<<(8192*64)/256, 256, 0, stream>>>(W2, W2T, l);
    k_conv    <<<NN/64, 256, 0, stream>>>(ug, h, W2T, row_ptr, edge_id, src_sorted, num, Hs);
    k_update  <<<NN/4, 256, 0, stream>>>(x_cur, num, h, Hs, deg, root, b2, convb, l);
  }
  k_dense_pool<<<NN/4, 256, 0, stream>>>(x_cur, dW, db, batch, pooled);
  k_final     <<<GG, 128, 0, stream>>>(pooled, cnt, oW, ob, out);
}

// Round 6
// 786.296 us; speedup vs baseline: 2.3136x; 2.3136x over previous
//
#include <hip/hip_runtime.h>
#include <hip/hip_bf16.h>

// Problem constants (from reference)
#define NN 16384
#define EE 65536
#define DD 64
#define HH 128
#define LL 3
#define GG 512
#define OUTD 128
#define NEG 0.01f   // jax.nn.leaky_relu default slope

#define CHUNK 8192   // nodes per S chunk (S = CHUNK x 8192 bf16 = 128 MiB)
#define KSEG 8       // split-K partial buffers

typedef __attribute__((ext_vector_type(8))) short short8;
typedef __attribute__((ext_vector_type(4))) float f32x4;

__device__ __forceinline__ float leaky(float x){ return x > 0.f ? x : NEG * x; }
__device__ __forceinline__ unsigned short f2bf(float f){
  union { float f; unsigned int u; } v; v.f = f;
  unsigned int r = v.u + 0x7fffu + ((v.u >> 16) & 1u);   // RNE
  return (unsigned short)(r >> 16);
}

// ---------------- CSR build ----------------
__global__ void k_deg(const int* ei, int* deg){
  int e = blockIdx.x*256 + threadIdx.x;
  if (e < EE) atomicAdd(&deg[ei[EE + e]], 1);   // row 1 of edge_index = dst
}
__global__ void k_cnt(const int* batch, int* cnt){
  int n = blockIdx.x*256 + threadIdx.x;
  if (n < NN) atomicAdd(&cnt[batch[n]], 1);
}
__global__ void k_scan(const int* deg, int* row_ptr){
  __shared__ int part[256];
  int t = threadIdx.x;
  int base = t*64; int s = 0;
  for (int i=0;i<64;++i) s += deg[base+i];
  part[t] = s; __syncthreads();
  for (int off=1; off<256; off<<=1){
    int v = (t>=off)?part[t-off]:0; __syncthreads();
    part[t] += v; __syncthreads();
  }
  int run = (t==0)?0:part[t-1];
  if (t==0) row_ptr[0] = 0;
  for (int i=0;i<64;++i){ run += deg[base+i]; row_ptr[base+i+1] = run; }
}
__global__ void k_fill(const int* ei, const int* row_ptr, int* cursor,
                       int* edge_id, int* src_sorted){
  int e = blockIdx.x*256 + threadIdx.x;
  if (e < EE){
    int d = ei[EE + e];
    int pos = row_ptr[d] + atomicAdd(&cursor[d], 1);
    edge_id[pos] = e;
    src_sorted[pos] = ei[e];      // row 0 of edge_index = src
  }
}

// ---------------- one-time bf16 prep: ea and W1^T ----------------
__global__ void k_prep_ea(const float* ea, unsigned short* eab){
  int i = blockIdx.x*256 + threadIdx.x;   // EE*DD
  eab[i] = f2bf(ea[i]);
}
__global__ void k_prep_w1t(const float* W1, unsigned short* W1T){
  int i = blockIdx.x*256 + threadIdx.x;   // LL*HH*DD
  int l = i >> 13, r = i & 8191;
  int j = r >> 6, d = r & 63;
  W1T[i] = f2bf(W1[(size_t)l*DD*HH + d*HH + j]);   // W1T[l][j][d]
}

// ---------------- LayerNorm + leaky ----------------
__global__ void k_ln(const float* x, const float* scale, const float* bias, float* h, int l){
  int t = threadIdx.x, lane = t & 63, nl = t >> 6;
  int n = blockIdx.x*4 + nl;
  float v = x[(size_t)n*DD + lane];
  float s = v;
  for (int m=1;m<64;m<<=1) s += __shfl_xor(s, m, 64);
  float mu = s * (1.0f/64.0f);
  float dv = v - mu;
  float q = dv*dv;
  for (int m=1;m<64;m<<=1) q += __shfl_xor(q, m, 64);
  float var = q * (1.0f/64.0f);
  float w = dv * rsqrtf(var + 1e-5f) * scale[l*DD + lane] + bias[l*DD + lane];
  h[(size_t)n*DD + lane] = leaky(w);
}

// ---------------- edge MLP via MFMA: ug = bf16(leaky(ea @ W1[l] + b1[l]))  [E,128] ----------
__global__ __launch_bounds__(256, 2)
void k_edge_mlp(const unsigned short* eab, const unsigned short* W1T, const float* b1,
                unsigned short* ug, int l){
  __shared__ __align__(16) unsigned short a_lds[128][72];   // ea tile  [e][d]
  __shared__ __align__(16) unsigned short b_lds[128][72];   // W1T      [j][d]
  __shared__ __align__(16) unsigned short c_lds[128][136];  // out      [e][j]
  int t = threadIdx.x;
  int e0 = blockIdx.x * 128;
  {
    int row = t >> 1, col = (t & 1) * 32;
    const float4* sa = (const float4*)(eab + (size_t)(e0 + row)*DD + col);
    const float4* sb = (const float4*)(W1T + (size_t)l*HH*DD + (size_t)row*DD + col);
    #pragma unroll
    for (int i=0;i<4;++i){
      *(float4*)&a_lds[row][col + 8*i] = sa[i];
      *(float4*)&b_lds[row][col + 8*i] = sb[i];
    }
  }
  __syncthreads();
  int wave = t >> 6, lane = t & 63;
  int m0 = (wave >> 1) * 64, j0 = (wave & 1) * 64;
  int lr = lane & 15, lq = lane >> 4;
  f32x4 acc[4][4];
  #pragma unroll
  for (int a=0;a<4;++a)
    #pragma unroll
    for (int b=0;b<4;++b) acc[a][b] = (f32x4){0.f,0.f,0.f,0.f};
  #pragma unroll
  for (int ks=0; ks<2; ++ks){
    short8 av[4];
    #pragma unroll
    for (int mt=0; mt<4; ++mt) av[mt] = *(const short8*)&a_lds[m0 + mt*16 + lr][ks*32 + lq*8];
    #pragma unroll
    for (int jt=0; jt<4; ++jt){
      short8 bv = *(const short8*)&b_lds[j0 + jt*16 + lr][ks*32 + lq*8];
      #pragma unroll
      for (int mt=0; mt<4; ++mt)
        acc[mt][jt] = __builtin_amdgcn_mfma_f32_16x16x32_bf16(av[mt], bv, acc[mt][jt], 0, 0, 0);
    }
  }
  // C/D: col = lane&15, row = (lane>>4)*4 + r
  #pragma unroll
  for (int mt=0; mt<4; ++mt)
    #pragma unroll
    for (int jt=0; jt<4; ++jt){
      int col = j0 + jt*16 + lr;
      float bj = b1[l*HH + col];
      #pragma unroll
      for (int r=0; r<4; ++r){
        int row = m0 + mt*16 + lq*4 + r;
        c_lds[row][col] = f2bf(leaky(acc[mt][jt][r] + bj));
      }
    }
  __syncthreads();
  {
    int row = t >> 1, half = t & 1;
    float4* dst = (float4*)(ug + (size_t)(e0 + row)*HH + half*64);
    #pragma unroll
    for (int i=0;i<8;++i) dst[i] = *(const float4*)&c_lds[row][half*64 + 8*i];
  }
}

// ---------------- W2[l] -> bf16 transposed [f][kd]  (kd = k*64+d, contiguous K) ----------------
__global__ void k_w2t(const float* W2, unsigned short* W2T, int l){
  int idx = blockIdx.x*256 + threadIdx.x;    // < 64*8192
  int f = idx >> 13, kd = idx & 8191;
  W2T[idx] = f2bf(W2[(size_t)l*HH*DD*DD + (size_t)kd*DD + f]);
}

// ---------------- S-build: register-resident outer-product, edge loop unrolled x2 -------------
// One wave per node. Lane owns k = {2*lane, 2*lane+1}; all 64 d in acc regs;
// h broadcast via v_readlane. Unroll-2 puts two edges' loads in flight.
__global__ __launch_bounds__(256, 2)
void k_sbuild2(const unsigned short* ug, const float* h, const int* row_ptr,
               const int* edge_id, const int* src_sorted,
               unsigned short* S, float* Hs, int chunk_base){
  int t = threadIdx.x, wave = t >> 6, lane = t & 63;
  int nloc = blockIdx.x*4 + wave;
  int n = chunk_base + nloc;
  int r0 = row_ptr[n], r1 = row_ptr[n+1];
  float acc0[64], acc1[64];
  #pragma unroll
  for (int d=0; d<64; ++d){ acc0[d] = 0.f; acc1[d] = 0.f; }
  float hs = 0.f;
  int pos = r0;
  for (; pos + 2 <= r1; pos += 2){
    int e0 = edge_id[pos],    e1 = edge_id[pos+1];
    int s0 = src_sorted[pos], s1 = src_sorted[pos+1];
    float hv0 = h[(size_t)s0*DD + lane];
    float hv1 = h[(size_t)s1*DD + lane];
    unsigned int q0 = *(const unsigned int*)(ug + (size_t)e0*HH + 2*lane);
    unsigned int q1 = *(const unsigned int*)(ug + (size_t)e1*HH + 2*lane);
    float u00 = __uint_as_float(q0 << 16), u01 = __uint_as_float(q0 & 0xFFFF0000u);
    float u10 = __uint_as_float(q1 << 16), u11 = __uint_as_float(q1 & 0xFFFF0000u);
    hs += hv0 + hv1;
    int h0 = __float_as_int(hv0), h1 = __float_as_int(hv1);
    #pragma unroll
    for (int d=0; d<64; ++d){
      float sh0 = __int_as_float(__builtin_amdgcn_readlane(h0, d));
      float sh1 = __int_as_float(__builtin_amdgcn_readlane(h1, d));
      acc0[d] += u00*sh0; acc0[d] += u10*sh1;
      acc1[d] += u01*sh0; acc1[d] += u11*sh1;
    }
  }
  if (pos < r1){
    int e = edge_id[pos];
    int s = src_sorted[pos];
    float hv = h[(size_t)s*DD + lane];
    unsigned int up = *(const unsigned int*)(ug + (size_t)e*HH + 2*lane);
    float u0 = __uint_as_float(up << 16);
    float u1 = __uint_as_float(up & 0xFFFF0000u);
    hs += hv;
    int hvi = __float_as_int(hv);
    #pragma unroll
    for (int d=0; d<64; ++d){
      float sh = __int_as_float(__builtin_amdgcn_readlane(hvi, d));
      acc0[d] += u0 * sh;
      acc1[d] += u1 * sh;
    }
  }
  unsigned short* Srow = S + (size_t)nloc*8192;
  #pragma unroll
  for (int k2=0; k2<2; ++k2){
    union { unsigned int u[32]; float4 v[8]; } buf;
    #pragma unroll
    for (int i=0;i<32;++i){
      float a0 = k2 ? acc1[2*i]   : acc0[2*i];
      float a1 = k2 ? acc1[2*i+1] : acc0[2*i+1];
      buf.u[i] = (unsigned int)f2bf(a0) | ((unsigned int)f2bf(a1) << 16);
    }
    float4* dst = (float4*)(Srow + (size_t)(2*lane + k2)*64);
    #pragma unroll
    for (int i=0;i<8;++i) dst[i] = buf.v[i];
  }
  Hs[(size_t)n*DD + lane] = hs;
}

// ---------------- GEMM: num_part[kseg][rows,64] = S[CHUNK,8192] @ W2T^T (bf16 MFMA) ----------
// Direct stores -- each (rowblk,kseg) block owns its output rows, no atomics.
__global__ void k_gemm(const unsigned short* S, const unsigned short* W2T,
                       float* num_part, int chunk_base){
  __shared__ __align__(16) unsigned short a_lds[128][72];  // +8 pad: conflict-free b128
  __shared__ __align__(16) unsigned short b_lds[64][72];
  int t = threadIdx.x;
  int wave = t >> 6, lane = t & 63;
  int rowblk = blockIdx.x, kseg = blockIdx.y;  // 64 x 8
  int lr = lane & 15, lq = lane >> 4;
  f32x4 acc[2][4];
  for (int a=0;a<2;++a) for (int b=0;b<4;++b) acc[a][b] = (f32x4){0.f,0.f,0.f,0.f};
  int m0 = wave * 32;
  for (int it = 0; it < 16; ++it){            // 16 x 64 = 1024 kd per kseg
    int kbase = kseg*1024 + it*64;
    #pragma unroll
    for (int ii=0; ii<4; ++ii){               // stage A: 128 rows x 64 kd
      int idx = t + 256*ii;
      int r = idx >> 3, c8 = (idx & 7) << 3;
      float4 v = *(const float4*)(S + (size_t)(rowblk*128 + r)*8192 + kbase + c8);
      *(float4*)&a_lds[r][c8] = v;
    }
    #pragma unroll
    for (int ii=0; ii<2; ++ii){               // stage B: 64 f x 64 kd (transposed W2)
      int idx = t + 256*ii;
      int r = idx >> 3, c8 = (idx & 7) << 3;
      float4 v = *(const float4*)(W2T + (size_t)r*8192 + kbase + c8);
      *(float4*)&b_lds[r][c8] = v;
    }
    __syncthreads();
    #pragma unroll
    for (int kk=0; kk<64; kk+=32){
      short8 a0 = *(const short8*)&a_lds[m0 + lr][kk + lq*8];
      short8 a1 = *(const short8*)&a_lds[m0 + 16 + lr][kk + lq*8];
      #pragma unroll
      for (int ft=0; ft<4; ++ft){
        short8 b = *(const short8*)&b_lds[ft*16 + lr][kk + lq*8];
        acc[0][ft] = __builtin_amdgcn_mfma_f32_16x16x32_bf16(a0, b, acc[0][ft], 0, 0, 0);
        acc[1][ft] = __builtin_amdgcn_mfma_f32_16x16x32_bf16(a1, b, acc[1][ft], 0, 0, 0);
      }
    }
    __syncthreads();
  }
  // C/D layout: col = lane&15, row = (lane>>4)*4 + reg   [m89/m91 verified]
  float* dstp = num_part + (size_t)kseg*NN*DD;
  #pragma unroll
  for (int rt=0; rt<2; ++rt)
    #pragma unroll
    for (int ft=0; ft<4; ++ft)
      #pragma unroll
      for (int r=0; r<4; ++r){
        int m = m0 + rt*16 + lq*4 + r;
        int f = ft*16 + lr;
        int n = chunk_base + rowblk*128 + m;
        dstp[(size_t)n*DD + f] = acc[rt][ft][r];
      }
}

// ---------------- node update: x += (sum_p num_part)/deg + h@root + Hs@b2 + conv_b ------------
__global__ void k_update(float* x, const float* num_part, const float* h, const float* Hs,
                         const int* deg, const float* root, const float* b2,
                         const float* conv_b, int l){
  __shared__ float rl[64][64];
  __shared__ float b2l[64][64];
  __shared__ float hrow[4][64];
  __shared__ float hsrow[4][64];
  int t = threadIdx.x;
  int f = t & 63, nl = t >> 6;
  for (int idx=t; idx<4096; idx+=256){
    rl[idx>>6][idx&63]  = root[(size_t)l*4096 + idx];
    b2l[idx>>6][idx&63] = b2[(size_t)l*4096 + idx];
  }
  int n = blockIdx.x*4 + nl;
  hrow[nl][f]  = h[(size_t)n*DD + f];
  hsrow[nl][f] = Hs[(size_t)n*DD + f];
  __syncthreads();
  float dg = (float)deg[n]; if (dg < 1.f) dg = 1.f;
  float nsum = 0.f;
  #pragma unroll
  for (int p=0; p<KSEG; ++p) nsum += num_part[(size_t)p*NN*DD + (size_t)n*DD + f];
  float acc = x[(size_t)n*DD + f] + nsum/dg + conv_b[l*DD + f];
  #pragma unroll
  for (int d=0; d<64; ++d)
    acc += hrow[nl][d]*rl[d][f] + hsrow[nl][d]*b2l[d][f];
  x[(size_t)n*DD + f] = acc;
}

// ---------------- head: dense + pooled atomic accumulate ----------------
__global__ void k_dense_pool(const float* x, const float* dW, const float* db,
                             const int* batch, float* pooled){
  __shared__ float wl[64][64];
  __shared__ float xrow[4][64];
  int t = threadIdx.x;
  int f = t & 63, nl = t >> 6;
  for (int idx=t; idx<4096; idx+=256) wl[idx>>6][idx&63] = dW[idx];
  int n = blockIdx.x*4 + nl;
  xrow[nl][f] = x[(size_t)n*DD + f];
  __syncthreads();
  float acc = db[f];
  #pragma unroll
  for (int d=0; d<64; ++d) acc += xrow[nl][d]*wl[d][f];
  atomicAdd(&pooled[(size_t)batch[n]*DD + f], acc);
}

__global__ void k_final(const float* pooled, const int* cnt, const float* oW,
                        const float* ob, float* out){
  __shared__ float p[64];
  int g = blockIdx.x, t = threadIdx.x;
  if (t < 64){
    float c = (float)cnt[g]; if (c < 1.f) c = 1.f;
    p[t] = leaky(pooled[(size_t)g*DD + t] / c);
  }
  __syncthreads();
  float acc = ob[t];
  #pragma unroll
  for (int f=0; f<64; ++f) acc += p[f]*oW[(size_t)f*OUTD + t];
  out[(size_t)g*OUTD + t] = acc;
}

// ws too small -> emit ws_size as diagnostic (deterministic per machine)
__global__ void k_diag(float* out, float val, int n){
  int i = blockIdx.x*256 + threadIdx.x;
  if (i < n) out[i] = (i==0) ? val : 0.f;
}

extern "C" void kernel_launch(void* const* d_in, const int* in_sizes, int n_in,
                              void* d_out, int out_size, void* d_ws, size_t ws_size,
                              hipStream_t stream){
  const float* x_in  = (const float*)d_in[0];
  const int*   ei    = (const int*)d_in[1];
  const float* ea    = (const float*)d_in[2];
  const int*   batch = (const int*)d_in[3];
  const float* ln_s  = (const float*)d_in[4];
  const float* ln_b  = (const float*)d_in[5];
  const float* W1    = (const float*)d_in[6];
  const float* b1    = (const float*)d_in[7];
  const float* W2    = (const float*)d_in[8];
  const float* b2    = (const float*)d_in[9];
  const float* root  = (const float*)d_in[10];
  const float* convb = (const float*)d_in[11];
  const float* dW    = (const float*)d_in[12];
  const float* db    = (const float*)d_in[13];
  const float* oW    = (const float*)d_in[14];
  const float* ob    = (const float*)d_in[15];
  float* out = (float*)d_out;

  char* ws = (char*)d_ws;
  size_t off = 0;
  auto alloc = [&](size_t bytes)->char*{
    char* p = ws + off; off = (off + bytes + 255) & ~(size_t)255; return p;
  };
  float* x_cur  = (float*)alloc((size_t)NN*DD*4);
  float* h      = (float*)alloc((size_t)NN*DD*4);
  unsigned short* ug  = (unsigned short*)alloc((size_t)EE*HH*2);
  float* num_part = (float*)alloc((size_t)KSEG*NN*DD*4);
  float* Hs     = (float*)alloc((size_t)NN*DD*4);
  unsigned short* S   = (unsigned short*)alloc((size_t)CHUNK*8192*2);
  unsigned short* W2T = (unsigned short*)alloc((size_t)8192*64*2);
  unsigned short* eab = (unsigned short*)alloc((size_t)EE*DD*2);
  unsigned short* W1T = (unsigned short*)alloc((size_t)LL*HH*DD*2);
  int* deg     = (int*)alloc((size_t)NN*4);
  int* row_ptr = (int*)alloc((size_t)(NN+1)*4);
  int* cursor  = (int*)alloc((size_t)NN*4);
  int* edge_id = (int*)alloc((size_t)EE*4);
  int* src_sorted = (int*)alloc((size_t)EE*4);
  int* cnt     = (int*)alloc((size_t)GG*4);
  float* pooled= (float*)alloc((size_t)GG*DD*4);
  size_t needed = off;
  if (ws_size < needed){
    k_diag<<<(out_size+255)/256, 256, 0, stream>>>(out, (float)ws_size, out_size);
    return;
  }

  hipMemsetAsync(deg, 0, (size_t)NN*4, stream);
  hipMemsetAsync(cursor, 0, (size_t)NN*4, stream);
  hipMemsetAsync(cnt, 0, (size_t)GG*4, stream);
  hipMemsetAsync(pooled, 0, (size_t)GG*DD*4, stream);
  hipMemcpyAsync(x_cur, x_in, (size_t)NN*DD*4, hipMemcpyDeviceToDevice, stream);

  k_deg <<<EE/256, 256, 0, stream>>>(ei, deg);
  k_cnt <<<NN/256, 256, 0, stream>>>(batch, cnt);
  k_scan<<<1, 256, 0, stream>>>(deg, row_ptr);
  k_fill<<<EE/256, 256, 0, stream>>>(ei, row_ptr, cursor, edge_id, src_sorted);
  k_prep_ea <<<(EE*DD)/256, 256, 0, stream>>>(ea, eab);
  k_prep_w1t<<<(LL*HH*DD)/256, 256, 0, stream>>>(W1, W1T);

  for (int l=0; l<LL; ++l){
    k_ln      <<<NN/4, 256, 0, stream>>>(x_cur, ln_s, ln_b, h, l);
    k_edge_mlp<<<EE/128, 256, 0, stream>>>(eab, W1T, b1, ug, l);
    k_w2t     <<<(8192*64)/256, 256, 0, stream>>>(W2, W2T, l);
    for (int c=0; c<NN/CHUNK; ++c){
      k_sbuild2<<<CHUNK/4, 256, 0, stream>>>(ug, h, row_ptr, edge_id, src_sorted, S, Hs, c*CHUNK);
      k_gemm   <<<dim3(CHUNK/128, KSEG), 256, 0, stream>>>(S, W2T, num_part, c*CHUNK);
    }
    k_update<<<NN/4, 256, 0, stream>>>(x_cur, num_part, h, Hs, deg, root, b2, convb, l);
  }
  k_dense_pool<<<NN/4, 256, 0, stream>>>(x_cur, dW, db, batch, pooled);
  k_final     <<<GG, 128, 0, stream>>>(pooled, cnt, oW, ob, out);
}

// Round 7
// 638.628 us; speedup vs baseline: 2.8486x; 1.2312x over previous
//
#include <hip/hip_runtime.h>
#include <hip/hip_bf16.h>

// Problem constants (from reference)
#define NN 16384
#define EE 65536
#define DD 64
#define HH 128
#define LL 3
#define GG 512
#define OUTD 128
#define NEG 0.01f   // jax.nn.leaky_relu default slope

#define CHUNK 8192   // nodes per S chunk (S = CHUNK x 8192 bf16 = 128 MiB)
#define KSEG 8       // split-K partial buffers

// S column permutation: S' stored in sbuild's writer-natural order.
// c' bits: [12]=k2, [11:9]=i, [8:3]=lane, [2:0]=w ; kd = 128*lane + 64*k2 + 8*i + w.
// W2T' bakes the same permutation, so gemm dots over c' directly.

typedef __attribute__((ext_vector_type(8))) short short8;
typedef __attribute__((ext_vector_type(4))) float f32x4;

__device__ __forceinline__ float leaky(float x){ return x > 0.f ? x : NEG * x; }
__device__ __forceinline__ unsigned short f2bf(float f){
  union { float f; unsigned int u; } v; v.f = f;
  unsigned int r = v.u + 0x7fffu + ((v.u >> 16) & 1u);   // RNE
  return (unsigned short)(r >> 16);
}

// ---------------- CSR build ----------------
__global__ void k_deg(const int* ei, int* deg){
  int e = blockIdx.x*256 + threadIdx.x;
  if (e < EE) atomicAdd(&deg[ei[EE + e]], 1);   // row 1 of edge_index = dst
}
__global__ void k_cnt(const int* batch, int* cnt){
  int n = blockIdx.x*256 + threadIdx.x;
  if (n < NN) atomicAdd(&cnt[batch[n]], 1);
}
__global__ void k_scan(const int* deg, int* row_ptr){
  __shared__ int part[256];
  int t = threadIdx.x;
  int base = t*64; int s = 0;
  for (int i=0;i<64;++i) s += deg[base+i];
  part[t] = s; __syncthreads();
  for (int off=1; off<256; off<<=1){
    int v = (t>=off)?part[t-off]:0; __syncthreads();
    part[t] += v; __syncthreads();
  }
  int run = (t==0)?0:part[t-1];
  if (t==0) row_ptr[0] = 0;
  for (int i=0;i<64;++i){ run += deg[base+i]; row_ptr[base+i+1] = run; }
}
__global__ void k_fill(const int* ei, const int* row_ptr, int* cursor,
                       int* edge_id, int* src_sorted){
  int e = blockIdx.x*256 + threadIdx.x;
  if (e < EE){
    int d = ei[EE + e];
    int pos = row_ptr[d] + atomicAdd(&cursor[d], 1);
    edge_id[pos] = e;
    src_sorted[pos] = ei[e];      // row 0 of edge_index = src
  }
}

// ---------------- one-time bf16 prep: ea and W1^T ----------------
__global__ void k_prep_ea(const float* ea, unsigned short* eab){
  int i = blockIdx.x*256 + threadIdx.x;   // EE*DD
  eab[i] = f2bf(ea[i]);
}
__global__ void k_prep_w1t(const float* W1, unsigned short* W1T){
  int i = blockIdx.x*256 + threadIdx.x;   // LL*HH*DD
  int l = i >> 13, r = i & 8191;
  int j = r >> 6, d = r & 63;
  W1T[i] = f2bf(W1[(size_t)l*DD*HH + d*HH + j]);   // W1T[l][j][d]
}

// ---------------- LayerNorm + leaky ----------------
__global__ void k_ln(const float* x, const float* scale, const float* bias, float* h, int l){
  int t = threadIdx.x, lane = t & 63, nl = t >> 6;
  int n = blockIdx.x*4 + nl;
  float v = x[(size_t)n*DD + lane];
  float s = v;
  for (int m=1;m<64;m<<=1) s += __shfl_xor(s, m, 64);
  float mu = s * (1.0f/64.0f);
  float dv = v - mu;
  float q = dv*dv;
  for (int m=1;m<64;m<<=1) q += __shfl_xor(q, m, 64);
  float var = q * (1.0f/64.0f);
  float w = dv * rsqrtf(var + 1e-5f) * scale[l*DD + lane] + bias[l*DD + lane];
  h[(size_t)n*DD + lane] = leaky(w);
}

// ---------------- edge MLP via MFMA: ug = bf16(leaky(ea @ W1[l] + b1[l]))  [E,128] ----------
__global__ __launch_bounds__(256, 2)
void k_edge_mlp(const unsigned short* eab, const unsigned short* W1T, const float* b1,
                unsigned short* ug, int l){
  __shared__ __align__(16) unsigned short a_lds[128][72];   // ea tile  [e][d]
  __shared__ __align__(16) unsigned short b_lds[128][72];   // W1T      [j][d]
  __shared__ __align__(16) unsigned short c_lds[128][136];  // out      [e][j]
  int t = threadIdx.x;
  int e0 = blockIdx.x * 128;
  {
    int row = t >> 1, col = (t & 1) * 32;
    const float4* sa = (const float4*)(eab + (size_t)(e0 + row)*DD + col);
    const float4* sb = (const float4*)(W1T + (size_t)l*HH*DD + (size_t)row*DD + col);
    #pragma unroll
    for (int i=0;i<4;++i){
      *(float4*)&a_lds[row][col + 8*i] = sa[i];
      *(float4*)&b_lds[row][col + 8*i] = sb[i];
    }
  }
  __syncthreads();
  int wave = t >> 6, lane = t & 63;
  int m0 = (wave >> 1) * 64, j0 = (wave & 1) * 64;
  int lr = lane & 15, lq = lane >> 4;
  f32x4 acc[4][4];
  #pragma unroll
  for (int a=0;a<4;++a)
    #pragma unroll
    for (int b=0;b<4;++b) acc[a][b] = (f32x4){0.f,0.f,0.f,0.f};
  #pragma unroll
  for (int ks=0; ks<2; ++ks){
    short8 av[4];
    #pragma unroll
    for (int mt=0; mt<4; ++mt) av[mt] = *(const short8*)&a_lds[m0 + mt*16 + lr][ks*32 + lq*8];
    #pragma unroll
    for (int jt=0; jt<4; ++jt){
      short8 bv = *(const short8*)&b_lds[j0 + jt*16 + lr][ks*32 + lq*8];
      #pragma unroll
      for (int mt=0; mt<4; ++mt)
        acc[mt][jt] = __builtin_amdgcn_mfma_f32_16x16x32_bf16(av[mt], bv, acc[mt][jt], 0, 0, 0);
    }
  }
  // C/D: col = lane&15, row = (lane>>4)*4 + r
  #pragma unroll
  for (int mt=0; mt<4; ++mt)
    #pragma unroll
    for (int jt=0; jt<4; ++jt){
      int col = j0 + jt*16 + lr;
      float bj = b1[l*HH + col];
      #pragma unroll
      for (int r=0; r<4; ++r){
        int row = m0 + mt*16 + lq*4 + r;
        c_lds[row][col] = f2bf(leaky(acc[mt][jt][r] + bj));
      }
    }
  __syncthreads();
  {
    int row = t >> 1, half = t & 1;
    float4* dst = (float4*)(ug + (size_t)(e0 + row)*HH + half*64);
    #pragma unroll
    for (int i=0;i<8;++i) dst[i] = *(const float4*)&c_lds[row][half*64 + 8*i];
  }
}

// ---------------- W2[l] -> bf16, permuted-transposed: W2T'[f][c'] = W2[kd(c')][f] ------------
__global__ void k_w2t(const float* W2, unsigned short* W2T, int l){
  int idx = blockIdx.x*256 + threadIdx.x;    // < 64*8192
  int f = idx >> 13, c = idx & 8191;
  int kd = 128*((c>>3)&63) + 64*(c>>12) + 8*((c>>9)&7) + (c&7);
  W2T[idx] = f2bf(W2[(size_t)l*HH*DD*DD + (size_t)kd*DD + f]);
}

// ---------------- S-build: register-resident outer-product, edge loop unrolled x2 -------------
// One wave per node. Lane owns k = {2*lane, 2*lane+1}; all 64 d in acc regs;
// h broadcast via v_readlane. Stores go to the PERMUTED S layout: instruction
// (k2,i) writes one contiguous 1 KiB segment across the wave (fully coalesced).
__global__ __launch_bounds__(256, 2)
void k_sbuild2(const unsigned short* ug, const float* h, const int* row_ptr,
               const int* edge_id, const int* src_sorted,
               unsigned short* S, float* Hs, int chunk_base){
  int t = threadIdx.x, wave = t >> 6, lane = t & 63;
  int nloc = blockIdx.x*4 + wave;
  int n = chunk_base + nloc;
  int r0 = row_ptr[n], r1 = row_ptr[n+1];
  float acc0[64], acc1[64];
  #pragma unroll
  for (int d=0; d<64; ++d){ acc0[d] = 0.f; acc1[d] = 0.f; }
  float hs = 0.f;
  int pos = r0;
  for (; pos + 2 <= r1; pos += 2){
    int e0 = edge_id[pos],    e1 = edge_id[pos+1];
    int s0 = src_sorted[pos], s1 = src_sorted[pos+1];
    float hv0 = h[(size_t)s0*DD + lane];
    float hv1 = h[(size_t)s1*DD + lane];
    unsigned int q0 = *(const unsigned int*)(ug + (size_t)e0*HH + 2*lane);
    unsigned int q1 = *(const unsigned int*)(ug + (size_t)e1*HH + 2*lane);
    float u00 = __uint_as_float(q0 << 16), u01 = __uint_as_float(q0 & 0xFFFF0000u);
    float u10 = __uint_as_float(q1 << 16), u11 = __uint_as_float(q1 & 0xFFFF0000u);
    hs += hv0 + hv1;
    int h0 = __float_as_int(hv0), h1 = __float_as_int(hv1);
    #pragma unroll
    for (int d=0; d<64; ++d){
      float sh0 = __int_as_float(__builtin_amdgcn_readlane(h0, d));
      float sh1 = __int_as_float(__builtin_amdgcn_readlane(h1, d));
      acc0[d] += u00*sh0; acc0[d] += u10*sh1;
      acc1[d] += u01*sh0; acc1[d] += u11*sh1;
    }
  }
  if (pos < r1){
    int e = edge_id[pos];
    int s = src_sorted[pos];
    float hv = h[(size_t)s*DD + lane];
    unsigned int up = *(const unsigned int*)(ug + (size_t)e*HH + 2*lane);
    float u0 = __uint_as_float(up << 16);
    float u1 = __uint_as_float(up & 0xFFFF0000u);
    hs += hv;
    int hvi = __float_as_int(hv);
    #pragma unroll
    for (int d=0; d<64; ++d){
      float sh = __int_as_float(__builtin_amdgcn_readlane(hvi, d));
      acc0[d] += u0 * sh;
      acc1[d] += u1 * sh;
    }
  }
  // coalesced permuted stores: chunk index (k2*8+i)*64 + lane
  float4* Srow = (float4*)(S + (size_t)nloc*8192);
  #pragma unroll
  for (int k2=0; k2<2; ++k2){
    union { unsigned int u[32]; float4 v[8]; } buf;
    #pragma unroll
    for (int i=0;i<32;++i){
      float a0 = k2 ? acc1[2*i]   : acc0[2*i];
      float a1 = k2 ? acc1[2*i+1] : acc0[2*i+1];
      buf.u[i] = (unsigned int)f2bf(a0) | ((unsigned int)f2bf(a1) << 16);
    }
    #pragma unroll
    for (int i=0;i<8;++i)
      Srow[(k2*8 + i)*64 + lane] = buf.v[i];
  }
  Hs[(size_t)n*DD + lane] = hs;
}

// ---------------- GEMM: num_part[kseg][rows,64] = S'[CHUNK,8192] @ W2T'^T (bf16 MFMA) --------
// 64 rows per block; grid (CHUNK/64, KSEG) = 1024 blocks -> 4 blocks/CU.
__global__ __launch_bounds__(256, 4)
void k_gemm(const unsigned short* S, const unsigned short* W2T,
            float* num_part, int chunk_base){
  __shared__ __align__(16) unsigned short a_lds[64][72];  // +8 pad: conflict-free b128
  __shared__ __align__(16) unsigned short b_lds[64][72];
  int t = threadIdx.x;
  int wave = t >> 6, lane = t & 63;
  int rowblk = blockIdx.x, kseg = blockIdx.y;
  int lr = lane & 15, lq = lane >> 4;
  f32x4 acc[4];
  #pragma unroll
  for (int b=0;b<4;++b) acc[b] = (f32x4){0.f,0.f,0.f,0.f};
  int m0 = wave * 16;
  for (int it = 0; it < 16; ++it){            // 16 x 64 = 1024 kd per kseg
    int kbase = kseg*1024 + it*64;
    #pragma unroll
    for (int ii=0; ii<2; ++ii){               // stage A: 64 rows x 64 kd
      int idx = t + 256*ii;
      int r = idx >> 3, c8 = (idx & 7) << 3;
      float4 v = *(const float4*)(S + (size_t)(rowblk*64 + r)*8192 + kbase + c8);
      *(float4*)&a_lds[r][c8] = v;
    }
    #pragma unroll
    for (int ii=0; ii<2; ++ii){               // stage B: 64 f x 64 kd
      int idx = t + 256*ii;
      int r = idx >> 3, c8 = (idx & 7) << 3;
      float4 v = *(const float4*)(W2T + (size_t)r*8192 + kbase + c8);
      *(float4*)&b_lds[r][c8] = v;
    }
    __syncthreads();
    #pragma unroll
    for (int kk=0; kk<64; kk+=32){
      short8 av = *(const short8*)&a_lds[m0 + lr][kk + lq*8];
      #pragma unroll
      for (int ft=0; ft<4; ++ft){
        short8 bv = *(const short8*)&b_lds[ft*16 + lr][kk + lq*8];
        acc[ft] = __builtin_amdgcn_mfma_f32_16x16x32_bf16(av, bv, acc[ft], 0, 0, 0);
      }
    }
    __syncthreads();
  }
  // C/D layout: col = lane&15, row = (lane>>4)*4 + reg
  float* dstp = num_part + (size_t)kseg*NN*DD;
  #pragma unroll
  for (int ft=0; ft<4; ++ft)
    #pragma unroll
    for (int r=0; r<4; ++r){
      int m = m0 + lq*4 + r;
      int f = ft*16 + lr;
      int n = chunk_base + rowblk*64 + m;
      dstp[(size_t)n*DD + f] = acc[ft][r];
    }
}

// ---------------- node update: x += (sum_p num_part)/deg + h@root + Hs@b2 + conv_b ------------
__global__ void k_update(float* x, const float* num_part, const float* h, const float* Hs,
                         const int* deg, const float* root, const float* b2,
                         const float* conv_b, int l){
  __shared__ float rl[64][64];
  __shared__ float b2l[64][64];
  __shared__ float hrow[4][64];
  __shared__ float hsrow[4][64];
  int t = threadIdx.x;
  int f = t & 63, nl = t >> 6;
  for (int idx=t; idx<4096; idx+=256){
    rl[idx>>6][idx&63]  = root[(size_t)l*4096 + idx];
    b2l[idx>>6][idx&63] = b2[(size_t)l*4096 + idx];
  }
  int n = blockIdx.x*4 + nl;
  hrow[nl][f]  = h[(size_t)n*DD + f];
  hsrow[nl][f] = Hs[(size_t)n*DD + f];
  __syncthreads();
  float dg = (float)deg[n]; if (dg < 1.f) dg = 1.f;
  float nsum = 0.f;
  #pragma unroll
  for (int p=0; p<KSEG; ++p) nsum += num_part[(size_t)p*NN*DD + (size_t)n*DD + f];
  float acc = x[(size_t)n*DD + f] + nsum/dg + conv_b[l*DD + f];
  #pragma unroll
  for (int d=0; d<64; ++d)
    acc += hrow[nl][d]*rl[d][f] + hsrow[nl][d]*b2l[d][f];
  x[(size_t)n*DD + f] = acc;
}

// ---------------- head: dense + pooled atomic accumulate ----------------
__global__ void k_dense_pool(const float* x, const float* dW, const float* db,
                             const int* batch, float* pooled){
  __shared__ float wl[64][64];
  __shared__ float xrow[4][64];
  int t = threadIdx.x;
  int f = t & 63, nl = t >> 6;
  for (int idx=t; idx<4096; idx+=256) wl[idx>>6][idx&63] = dW[idx];
  int n = blockIdx.x*4 + nl;
  xrow[nl][f] = x[(size_t)n*DD + f];
  __syncthreads();
  float acc = db[f];
  #pragma unroll
  for (int d=0; d<64; ++d) acc += xrow[nl][d]*wl[d][f];
  atomicAdd(&pooled[(size_t)batch[n]*DD + f], acc);
}

__global__ void k_final(const float* pooled, const int* cnt, const float* oW,
                        const float* ob, float* out){
  __shared__ float p[64];
  int g = blockIdx.x, t = threadIdx.x;
  if (t < 64){
    float c = (float)cnt[g]; if (c < 1.f) c = 1.f;
    p[t] = leaky(pooled[(size_t)g*DD + t] / c);
  }
  __syncthreads();
  float acc = ob[t];
  #pragma unroll
  for (int f=0; f<64; ++f) acc += p[f]*oW[(size_t)f*OUTD + t];
  out[(size_t)g*OUTD + t] = acc;
}

// ws too small -> emit ws_size as diagnostic (deterministic per machine)
__global__ void k_diag(float* out, float val, int n){
  int i = blockIdx.x*256 + threadIdx.x;
  if (i < n) out[i] = (i==0) ? val : 0.f;
}

extern "C" void kernel_launch(void* const* d_in, const int* in_sizes, int n_in,
                              void* d_out, int out_size, void* d_ws, size_t ws_size,
                              hipStream_t stream){
  const float* x_in  = (const float*)d_in[0];
  const int*   ei    = (const int*)d_in[1];
  const float* ea    = (const float*)d_in[2];
  const int*   batch = (const int*)d_in[3];
  const float* ln_s  = (const float*)d_in[4];
  const float* ln_b  = (const float*)d_in[5];
  const float* W1    = (const float*)d_in[6];
  const float* b1    = (const float*)d_in[7];
  const float* W2    = (const float*)d_in[8];
  const float* b2    = (const float*)d_in[9];
  const float* root  = (const float*)d_in[10];
  const float* convb = (const float*)d_in[11];
  const float* dW    = (const float*)d_in[12];
  const float* db    = (const float*)d_in[13];
  const float* oW    = (const float*)d_in[14];
  const float* ob    = (const float*)d_in[15];
  float* out = (float*)d_out;

  char* ws = (char*)d_ws;
  size_t off = 0;
  auto alloc = [&](size_t bytes)->char*{
    char* p = ws + off; off = (off + bytes + 255) & ~(size_t)255; return p;
  };
  float* x_cur  = (float*)alloc((size_t)NN*DD*4);
  float* h      = (float*)alloc((size_t)NN*DD*4);
  unsigned short* ug  = (unsigned short*)alloc((size_t)EE*HH*2);
  float* num_part = (float*)alloc((size_t)KSEG*NN*DD*4);
  float* Hs     = (float*)alloc((size_t)NN*DD*4);
  unsigned short* S   = (unsigned short*)alloc((size_t)CHUNK*8192*2);
  unsigned short* W2T = (unsigned short*)alloc((size_t)8192*64*2);
  unsigned short* eab = (unsigned short*)alloc((size_t)EE*DD*2);
  unsigned short* W1T = (unsigned short*)alloc((size_t)LL*HH*DD*2);
  int* deg     = (int*)alloc((size_t)NN*4);
  int* row_ptr = (int*)alloc((size_t)(NN+1)*4);
  int* cursor  = (int*)alloc((size_t)NN*4);
  int* edge_id = (int*)alloc((size_t)EE*4);
  int* src_sorted = (int*)alloc((size_t)EE*4);
  int* cnt     = (int*)alloc((size_t)GG*4);
  float* pooled= (float*)alloc((size_t)GG*DD*4);
  size_t needed = off;
  if (ws_size < needed){
    k_diag<<<(out_size+255)/256, 256, 0, stream>>>(out, (float)ws_size, out_size);
    return;
  }

  hipMemsetAsync(deg, 0, (size_t)NN*4, stream);
  hipMemsetAsync(cursor, 0, (size_t)NN*4, stream);
  hipMemsetAsync(cnt, 0, (size_t)GG*4, stream);
  hipMemsetAsync(pooled, 0, (size_t)GG*DD*4, stream);
  hipMemcpyAsync(x_cur, x_in, (size_t)NN*DD*4, hipMemcpyDeviceToDevice, stream);

  k_deg <<<EE/256, 256, 0, stream>>>(ei, deg);
  k_cnt <<<NN/256, 256, 0, stream>>>(batch, cnt);
  k_scan<<<1, 256, 0, stream>>>(deg, row_ptr);
  k_fill<<<EE/256, 256, 0, stream>>>(ei, row_ptr, cursor, edge_id, src_sorted);
  k_prep_ea <<<(EE*DD)/256, 256, 0, stream>>>(ea, eab);
  k_prep_w1t<<<(LL*HH*DD)/256, 256, 0, stream>>>(W1, W1T);

  for (int l=0; l<LL; ++l){
    k_ln      <<<NN/4, 256, 0, stream>>>(x_cur, ln_s, ln_b, h, l);
    k_edge_mlp<<<EE/128, 256, 0, stream>>>(eab, W1T, b1, ug, l);
    k_w2t     <<<(8192*64)/256, 256, 0, stream>>>(W2, W2T, l);
    for (int c=0; c<NN/CHUNK; ++c){
      k_sbuild2<<<CHUNK/4, 256, 0, stream>>>(ug, h, row_ptr, edge_id, src_sorted, S, Hs, c*CHUNK);
      k_gemm   <<<dim3(CHUNK/64, KSEG), 256, 0, stream>>>(S, W2T, num_part, c*CHUNK);
    }
    k_update<<<NN/4, 256, 0, stream>>>(x_cur, num_part, h, Hs, deg, root, b2, convb, l);
  }
  k_dense_pool<<<NN/4, 256, 0, stream>>>(x_cur, dW, db, batch, pooled);
  k_final     <<<GG, 128, 0, stream>>>(pooled, cnt, oW, ob, out);
}

// Round 8
// 609.382 us; speedup vs baseline: 2.9853x; 1.0480x over previous
//
#include <hip/hip_runtime.h>
#include <hip/hip_bf16.h>

// Problem constants (from reference)
#define NN 16384
#define EE 65536
#define DD 64
#define HH 128
#define LL 3
#define GG 512
#define OUTD 128
#define NEG 0.01f   // jax.nn.leaky_relu default slope

#define CHUNK 8192   // nodes per S chunk (S = CHUNK x 8192 bf16 = 128 MiB)
#define KSEG 8       // split-K partial buffers

// S column permutation: S' stored in sbuild's writer-natural order.
// c' bits: [12]=k2, [11:9]=i, [8:3]=lane, [2:0]=w ; kd = 128*lane + 64*k2 + 8*i + w.
// W2T' bakes the same permutation, so gemm dots over c' directly.

typedef __attribute__((ext_vector_type(8))) short short8;
typedef __attribute__((ext_vector_type(4))) float f32x4;

__device__ __forceinline__ float leaky(float x){ return x > 0.f ? x : NEG * x; }
__device__ __forceinline__ unsigned short f2bf(float f){
  union { float f; unsigned int u; } v; v.f = f;
  unsigned int r = v.u + 0x7fffu + ((v.u >> 16) & 1u);   // RNE
  return (unsigned short)(r >> 16);
}

// ---------------- init: zero counters + copy x (replaces 4 memsets + 1 memcpy) ----------------
__global__ void k_init(const float* x_in, float* x_cur, int* deg, int* cursor,
                       int* cnt, float* pooled){
  int i = blockIdx.x*256 + threadIdx.x;    // grid 4096 -> NN*DD threads
  x_cur[i] = x_in[i];
  if (i < NN){ deg[i] = 0; cursor[i] = 0; }
  if (i < GG) cnt[i] = 0;
  if (i < GG*DD) pooled[i] = 0.f;
}

// ---------------- CSR build ----------------
__global__ void k_degcnt(const int* ei, const int* batch, int* deg, int* cnt){
  int e = blockIdx.x*256 + threadIdx.x;
  atomicAdd(&deg[ei[EE + e]], 1);          // row 1 of edge_index = dst
  if (e < NN) atomicAdd(&cnt[batch[e]], 1);
}
__global__ void k_scan(const int* deg, int* row_ptr){
  __shared__ int part[256];
  int t = threadIdx.x;
  int base = t*64; int s = 0;
  for (int i=0;i<64;++i) s += deg[base+i];
  part[t] = s; __syncthreads();
  for (int off=1; off<256; off<<=1){
    int v = (t>=off)?part[t-off]:0; __syncthreads();
    part[t] += v; __syncthreads();
  }
  int run = (t==0)?0:part[t-1];
  if (t==0) row_ptr[0] = 0;
  for (int i=0;i<64;++i){ run += deg[base+i]; row_ptr[base+i+1] = run; }
}
__global__ void k_fill(const int* ei, const int* row_ptr, int* cursor,
                       int* edge_id, int* src_sorted){
  int e = blockIdx.x*256 + threadIdx.x;
  if (e < EE){
    int d = ei[EE + e];
    int pos = row_ptr[d] + atomicAdd(&cursor[d], 1);
    edge_id[pos] = e;
    src_sorted[pos] = ei[e];      // row 0 of edge_index = src
  }
}

// ---------------- one-time bf16 conversions: eab, W1T, W2T (ALL layers, permuted) -------------
#define CV_A (EE*DD)            // 4194304
#define CV_B (LL*HH*DD)         // 24576
#define CV_C (LL*64*8192)       // 1572864
__global__ void k_convert(const float* ea, const float* W1, const float* W2,
                          unsigned short* eab, unsigned short* W1T, unsigned short* W2T){
  int idx = blockIdx.x*256 + threadIdx.x;
  if (idx < CV_A){
    eab[idx] = f2bf(ea[idx]);
  } else if (idx < CV_A + CV_B){
    int i = idx - CV_A;
    int l = i >> 13, r = i & 8191;
    int j = r >> 6, d = r & 63;
    W1T[i] = f2bf(W1[(size_t)l*DD*HH + d*HH + j]);   // W1T[l][j][d]
  } else {
    int i = idx - CV_A - CV_B;
    int l = i >> 19, rem = i & ((1<<19)-1);          // 64*8192 = 2^19 per layer
    int f = rem >> 13, c = rem & 8191;
    int kd = 128*((c>>3)&63) + 64*(c>>12) + 8*((c>>9)&7) + (c&7);
    W2T[i] = f2bf(W2[(size_t)l*HH*DD*DD + (size_t)kd*DD + f]);
  }
}

// ---------------- merged LayerNorm+leaky (blocks 0..NN/4) and edge-MLP MFMA (rest) ------------
__global__ __launch_bounds__(256, 2)
void k_lnmlp(const float* x, const float* scale, const float* bias, float* h,
             const unsigned short* eab, const unsigned short* W1T, const float* b1,
             unsigned short* ug, int l){
  __shared__ __align__(16) unsigned short a_lds[128][72];   // ea tile  [e][d]
  __shared__ __align__(16) unsigned short b_lds[128][72];   // W1T      [j][d]
  __shared__ __align__(16) unsigned short c_lds[128][136];  // out      [e][j]
  int t = threadIdx.x;
  if (blockIdx.x < NN/4){
    // ---- LayerNorm + leaky ----
    int lane = t & 63, nl = t >> 6;
    int n = blockIdx.x*4 + nl;
    float v = x[(size_t)n*DD + lane];
    float s = v;
    for (int m=1;m<64;m<<=1) s += __shfl_xor(s, m, 64);
    float mu = s * (1.0f/64.0f);
    float dv = v - mu;
    float q = dv*dv;
    for (int m=1;m<64;m<<=1) q += __shfl_xor(q, m, 64);
    float var = q * (1.0f/64.0f);
    float w = dv * rsqrtf(var + 1e-5f) * scale[l*DD + lane] + bias[l*DD + lane];
    h[(size_t)n*DD + lane] = leaky(w);
    return;
  }
  // ---- edge MLP: ug = bf16(leaky(ea @ W1[l] + b1[l])) ----
  int e0 = (blockIdx.x - NN/4) * 128;
  {
    int row = t >> 1, col = (t & 1) * 32;
    const float4* sa = (const float4*)(eab + (size_t)(e0 + row)*DD + col);
    const float4* sb = (const float4*)(W1T + (size_t)l*HH*DD + (size_t)row*DD + col);
    #pragma unroll
    for (int i=0;i<4;++i){
      *(float4*)&a_lds[row][col + 8*i] = sa[i];
      *(float4*)&b_lds[row][col + 8*i] = sb[i];
    }
  }
  __syncthreads();
  int wave = t >> 6, lane = t & 63;
  int m0 = (wave >> 1) * 64, j0 = (wave & 1) * 64;
  int lr = lane & 15, lq = lane >> 4;
  f32x4 acc[4][4];
  #pragma unroll
  for (int a=0;a<4;++a)
    #pragma unroll
    for (int b=0;b<4;++b) acc[a][b] = (f32x4){0.f,0.f,0.f,0.f};
  #pragma unroll
  for (int ks=0; ks<2; ++ks){
    short8 av[4];
    #pragma unroll
    for (int mt=0; mt<4; ++mt) av[mt] = *(const short8*)&a_lds[m0 + mt*16 + lr][ks*32 + lq*8];
    #pragma unroll
    for (int jt=0; jt<4; ++jt){
      short8 bv = *(const short8*)&b_lds[j0 + jt*16 + lr][ks*32 + lq*8];
      #pragma unroll
      for (int mt=0; mt<4; ++mt)
        acc[mt][jt] = __builtin_amdgcn_mfma_f32_16x16x32_bf16(av[mt], bv, acc[mt][jt], 0, 0, 0);
    }
  }
  // C/D: col = lane&15, row = (lane>>4)*4 + r
  #pragma unroll
  for (int mt=0; mt<4; ++mt)
    #pragma unroll
    for (int jt=0; jt<4; ++jt){
      int col = j0 + jt*16 + lr;
      float bj = b1[l*HH + col];
      #pragma unroll
      for (int r=0; r<4; ++r){
        int row = m0 + mt*16 + lq*4 + r;
        c_lds[row][col] = f2bf(leaky(acc[mt][jt][r] + bj));
      }
    }
  __syncthreads();
  {
    int row = t >> 1, half = t & 1;
    float4* dst = (float4*)(ug + (size_t)(e0 + row)*HH + half*64);
    #pragma unroll
    for (int i=0;i<8;++i) dst[i] = *(const float4*)&c_lds[row][half*64 + 8*i];
  }
}

// ---------------- S-build: register-resident outer-product, edge loop unrolled x4 -------------
// One wave per node. Lane owns k = {2*lane, 2*lane+1}; all 64 d in acc regs;
// h broadcast via v_readlane. Coalesced permuted stores (1 KiB/instr per wave).
__global__ __launch_bounds__(256, 2)
void k_sbuild2(const unsigned short* ug, const float* h, const int* row_ptr,
               const int* edge_id, const int* src_sorted,
               unsigned short* S, float* Hs, int chunk_base){
  int t = threadIdx.x, wave = t >> 6, lane = t & 63;
  int nloc = blockIdx.x*4 + wave;
  int n = chunk_base + nloc;
  int r0 = row_ptr[n], r1 = row_ptr[n+1];
  float acc0[64], acc1[64];
  #pragma unroll
  for (int d=0; d<64; ++d){ acc0[d] = 0.f; acc1[d] = 0.f; }
  float hs = 0.f;
  int pos = r0;
  for (; pos + 4 <= r1; pos += 4){
    int e0 = edge_id[pos],   e1 = edge_id[pos+1],   e2 = edge_id[pos+2],   e3 = edge_id[pos+3];
    int s0 = src_sorted[pos],s1 = src_sorted[pos+1],s2 = src_sorted[pos+2],s3 = src_sorted[pos+3];
    float hv0 = h[(size_t)s0*DD + lane];
    float hv1 = h[(size_t)s1*DD + lane];
    float hv2 = h[(size_t)s2*DD + lane];
    float hv3 = h[(size_t)s3*DD + lane];
    unsigned int q0 = *(const unsigned int*)(ug + (size_t)e0*HH + 2*lane);
    unsigned int q1 = *(const unsigned int*)(ug + (size_t)e1*HH + 2*lane);
    unsigned int q2 = *(const unsigned int*)(ug + (size_t)e2*HH + 2*lane);
    unsigned int q3 = *(const unsigned int*)(ug + (size_t)e3*HH + 2*lane);
    float u00 = __uint_as_float(q0 << 16), u01 = __uint_as_float(q0 & 0xFFFF0000u);
    float u10 = __uint_as_float(q1 << 16), u11 = __uint_as_float(q1 & 0xFFFF0000u);
    float u20 = __uint_as_float(q2 << 16), u21 = __uint_as_float(q2 & 0xFFFF0000u);
    float u30 = __uint_as_float(q3 << 16), u31 = __uint_as_float(q3 & 0xFFFF0000u);
    hs += hv0 + hv1 + hv2 + hv3;
    int h0 = __float_as_int(hv0), h1 = __float_as_int(hv1);
    int h2 = __float_as_int(hv2), h3 = __float_as_int(hv3);
    #pragma unroll
    for (int d=0; d<64; ++d){
      float sh0 = __int_as_float(__builtin_amdgcn_readlane(h0, d));
      float sh1 = __int_as_float(__builtin_amdgcn_readlane(h1, d));
      float sh2 = __int_as_float(__builtin_amdgcn_readlane(h2, d));
      float sh3 = __int_as_float(__builtin_amdgcn_readlane(h3, d));
      acc0[d] += u00*sh0; acc1[d] += u01*sh0;
      acc0[d] += u10*sh1; acc1[d] += u11*sh1;
      acc0[d] += u20*sh2; acc1[d] += u21*sh2;
      acc0[d] += u30*sh3; acc1[d] += u31*sh3;
    }
  }
  for (; pos < r1; ++pos){
    int e = edge_id[pos];
    int s = src_sorted[pos];
    float hv = h[(size_t)s*DD + lane];
    unsigned int up = *(const unsigned int*)(ug + (size_t)e*HH + 2*lane);
    float u0 = __uint_as_float(up << 16);
    float u1 = __uint_as_float(up & 0xFFFF0000u);
    hs += hv;
    int hvi = __float_as_int(hv);
    #pragma unroll
    for (int d=0; d<64; ++d){
      float sh = __int_as_float(__builtin_amdgcn_readlane(hvi, d));
      acc0[d] += u0 * sh;
      acc1[d] += u1 * sh;
    }
  }
  // coalesced permuted stores: chunk index (k2*8+i)*64 + lane
  float4* Srow = (float4*)(S + (size_t)nloc*8192);
  #pragma unroll
  for (int k2=0; k2<2; ++k2){
    union { unsigned int u[32]; float4 v[8]; } buf;
    #pragma unroll
    for (int i=0;i<32;++i){
      float a0 = k2 ? acc1[2*i]   : acc0[2*i];
      float a1 = k2 ? acc1[2*i+1] : acc0[2*i+1];
      buf.u[i] = (unsigned int)f2bf(a0) | ((unsigned int)f2bf(a1) << 16);
    }
    #pragma unroll
    for (int i=0;i<8;++i)
      Srow[(k2*8 + i)*64 + lane] = buf.v[i];
  }
  Hs[(size_t)n*DD + lane] = hs;
}

// ---------------- GEMM: num_part[kseg][rows,64] = S'[CHUNK,8192] @ W2T'^T (bf16 MFMA) --------
// 64 rows per block, BK=128 (8 barrier-pairs per kseg); grid (CHUNK/64, KSEG) -> 4 blocks/CU.
__global__ __launch_bounds__(256, 4)
void k_gemm(const unsigned short* S, const unsigned short* W2T,
            float* num_part, int chunk_base){
  __shared__ __align__(16) unsigned short a_lds[64][136];  // +8 pad: conflict-free b128
  __shared__ __align__(16) unsigned short b_lds[64][136];
  int t = threadIdx.x;
  int wave = t >> 6, lane = t & 63;
  int rowblk = blockIdx.x, kseg = blockIdx.y;
  int lr = lane & 15, lq = lane >> 4;
  f32x4 acc[4];
  #pragma unroll
  for (int b=0;b<4;++b) acc[b] = (f32x4){0.f,0.f,0.f,0.f};
  int m0 = wave * 16;
  int r = t >> 2, q = t & 3;
  for (int it = 0; it < 8; ++it){             // 8 x 128 = 1024 kd per kseg
    int kbase = kseg*1024 + it*128;
    {
      const float4* sa = (const float4*)(S + (size_t)(rowblk*64 + r)*8192 + kbase);
      const float4* sb = (const float4*)(W2T + (size_t)r*8192 + kbase);
      float4* da = (float4*)&a_lds[r][0];
      float4* db = (float4*)&b_lds[r][0];
      #pragma unroll
      for (int i=0;i<4;++i){ da[q + 4*i] = sa[q + 4*i]; db[q + 4*i] = sb[q + 4*i]; }
    }
    __syncthreads();
    #pragma unroll
    for (int kk=0; kk<128; kk+=32){
      short8 av = *(const short8*)&a_lds[m0 + lr][kk + lq*8];
      #pragma unroll
      for (int ft=0; ft<4; ++ft){
        short8 bv = *(const short8*)&b_lds[ft*16 + lr][kk + lq*8];
        acc[ft] = __builtin_amdgcn_mfma_f32_16x16x32_bf16(av, bv, acc[ft], 0, 0, 0);
      }
    }
    __syncthreads();
  }
  // C/D layout: col = lane&15, row = (lane>>4)*4 + reg
  float* dstp = num_part + (size_t)kseg*NN*DD;
  #pragma unroll
  for (int ft=0; ft<4; ++ft)
    #pragma unroll
    for (int rr=0; rr<4; ++rr){
      int m = m0 + lq*4 + rr;
      int f = ft*16 + lr;
      int n = chunk_base + rowblk*64 + m;
      dstp[(size_t)n*DD + f] = acc[ft][rr];
    }
}

// ---------------- node update: x += (sum_p num_part)/deg + h@root + Hs@b2 + conv_b ------------
__global__ void k_update(float* x, const float* num_part, const float* h, const float* Hs,
                         const int* deg, const float* root, const float* b2,
                         const float* conv_b, int l){
  __shared__ float rl[64][64];
  __shared__ float b2l[64][64];
  __shared__ float hrow[4][64];
  __shared__ float hsrow[4][64];
  int t = threadIdx.x;
  int f = t & 63, nl = t >> 6;
  for (int idx=t; idx<4096; idx+=256){
    rl[idx>>6][idx&63]  = root[(size_t)l*4096 + idx];
    b2l[idx>>6][idx&63] = b2[(size_t)l*4096 + idx];
  }
  int n = blockIdx.x*4 + nl;
  hrow[nl][f]  = h[(size_t)n*DD + f];
  hsrow[nl][f] = Hs[(size_t)n*DD + f];
  __syncthreads();
  float dg = (float)deg[n]; if (dg < 1.f) dg = 1.f;
  float nsum = 0.f;
  #pragma unroll
  for (int p=0; p<KSEG; ++p) nsum += num_part[(size_t)p*NN*DD + (size_t)n*DD + f];
  float acc = x[(size_t)n*DD + f] + nsum/dg + conv_b[l*DD + f];
  #pragma unroll
  for (int d=0; d<64; ++d)
    acc += hrow[nl][d]*rl[d][f] + hsrow[nl][d]*b2l[d][f];
  x[(size_t)n*DD + f] = acc;
}

// ---------------- head: dense + pooled atomic accumulate ----------------
__global__ void k_dense_pool(const float* x, const float* dW, const float* db,
                             const int* batch, float* pooled){
  __shared__ float wl[64][64];
  __shared__ float xrow[4][64];
  int t = threadIdx.x;
  int f = t & 63, nl = t >> 6;
  for (int idx=t; idx<4096; idx+=256) wl[idx>>6][idx&63] = dW[idx];
  int n = blockIdx.x*4 + nl;
  xrow[nl][f] = x[(size_t)n*DD + f];
  __syncthreads();
  float acc = db[f];
  #pragma unroll
  for (int d=0; d<64; ++d) acc += xrow[nl][d]*wl[d][f];
  atomicAdd(&pooled[(size_t)batch[n]*DD + f], acc);
}

__global__ void k_final(const float* pooled, const int* cnt, const float* oW,
                        const float* ob, float* out){
  __shared__ float p[64];
  int g = blockIdx.x, t = threadIdx.x;
  if (t < 64){
    float c = (float)cnt[g]; if (c < 1.f) c = 1.f;
    p[t] = leaky(pooled[(size_t)g*DD + t] / c);
  }
  __syncthreads();
  float acc = ob[t];
  #pragma unroll
  for (int f=0; f<64; ++f) acc += p[f]*oW[(size_t)f*OUTD + t];
  out[(size_t)g*OUTD + t] = acc;
}

// ws too small -> emit ws_size as diagnostic (deterministic per machine)
__global__ void k_diag(float* out, float val, int n){
  int i = blockIdx.x*256 + threadIdx.x;
  if (i < n) out[i] = (i==0) ? val : 0.f;
}

extern "C" void kernel_launch(void* const* d_in, const int* in_sizes, int n_in,
                              void* d_out, int out_size, void* d_ws, size_t ws_size,
                              hipStream_t stream){
  const float* x_in  = (const float*)d_in[0];
  const int*   ei    = (const int*)d_in[1];
  const float* ea    = (const float*)d_in[2];
  const int*   batch = (const int*)d_in[3];
  const float* ln_s  = (const float*)d_in[4];
  const float* ln_b  = (const float*)d_in[5];
  const float* W1    = (const float*)d_in[6];
  const float* b1    = (const float*)d_in[7];
  const float* W2    = (const float*)d_in[8];
  const float* b2    = (const float*)d_in[9];
  const float* root  = (const float*)d_in[10];
  const float* convb = (const float*)d_in[11];
  const float* dW    = (const float*)d_in[12];
  const float* db    = (const float*)d_in[13];
  const float* oW    = (const float*)d_in[14];
  const float* ob    = (const float*)d_in[15];
  float* out = (float*)d_out;

  char* ws = (char*)d_ws;
  size_t off = 0;
  auto alloc = [&](size_t bytes)->char*{
    char* p = ws + off; off = (off + bytes + 255) & ~(size_t)255; return p;
  };
  float* x_cur  = (float*)alloc((size_t)NN*DD*4);
  float* h      = (float*)alloc((size_t)NN*DD*4);
  unsigned short* ug  = (unsigned short*)alloc((size_t)EE*HH*2);
  float* num_part = (float*)alloc((size_t)KSEG*NN*DD*4);
  float* Hs     = (float*)alloc((size_t)NN*DD*4);
  unsigned short* S   = (unsigned short*)alloc((size_t)CHUNK*8192*2);
  unsigned short* W2T = (unsigned short*)alloc((size_t)LL*8192*64*2);
  unsigned short* eab = (unsigned short*)alloc((size_t)EE*DD*2);
  unsigned short* W1T = (unsigned short*)alloc((size_t)LL*HH*DD*2);
  int* deg     = (int*)alloc((size_t)NN*4);
  int* row_ptr = (int*)alloc((size_t)(NN+1)*4);
  int* cursor  = (int*)alloc((size_t)NN*4);
  int* edge_id = (int*)alloc((size_t)EE*4);
  int* src_sorted = (int*)alloc((size_t)EE*4);
  int* cnt     = (int*)alloc((size_t)GG*4);
  float* pooled= (float*)alloc((size_t)GG*DD*4);
  size_t needed = off;
  if (ws_size < needed){
    k_diag<<<(out_size+255)/256, 256, 0, stream>>>(out, (float)ws_size, out_size);
    return;
  }

  k_init   <<<NN*DD/256, 256, 0, stream>>>(x_in, x_cur, deg, cursor, cnt, pooled);
  k_degcnt <<<EE/256, 256, 0, stream>>>(ei, batch, deg, cnt);
  k_scan   <<<1, 256, 0, stream>>>(deg, row_ptr);
  k_fill   <<<EE/256, 256, 0, stream>>>(ei, row_ptr, cursor, edge_id, src_sorted);
  k_convert<<<(CV_A+CV_B+CV_C)/256, 256, 0, stream>>>(ea, W1, W2, eab, W1T, W2T);

  for (int l=0; l<LL; ++l){
    k_lnmlp<<<NN/4 + EE/128, 256, 0, stream>>>(x_cur, ln_s, ln_b, h, eab, W1T, b1, ug, l);
    for (int c=0; c<NN/CHUNK; ++c){
      k_sbuild2<<<CHUNK/4, 256, 0, stream>>>(ug, h, row_ptr, edge_id, src_sorted, S, Hs, c*CHUNK);
      k_gemm   <<<dim3(CHUNK/64, KSEG), 256, 0, stream>>>(S, W2T + (size_t)l*8192*64, num_part, c*CHUNK);
    }
    k_update<<<NN/4, 256, 0, stream>>>(x_cur, num_part, h, Hs, deg, root, b2, convb, l);
  }
  k_dense_pool<<<NN/4, 256, 0, stream>>>(x_cur, dW, db, batch, pooled);
  k_final     <<<GG, 128, 0, stream>>>(pooled, cnt, oW, ob, out);
}